// Round 2
// baseline (247.881 us; speedup 1.0000x reference)
//
#include <hip/hip_runtime.h>
#include <stdint.h>

// Fully-fused binary conv: per-block {weight-pack, activation-pack-to-LDS,
// boundary-class base table, XNOR-popcount conv} in ONE dispatch.
// A: [32,64,112,112] f32, W: [64,64,3,3] f32 (flat), out: [32,64,112,112] f32.
// sign(x) bit = signbit(x); dot over 64 ch = 64 - 2*popc(a ^ w).
// Padding: LDS tile has a zeroed halo (bits 0 = all +1 signs); the spurious pad
// contribution is folded into bases[class][o]: out = bases - 2*s.

#define NN 32
#define CC 64
#define HH 112
#define WW 112
#define OO 64
#define HW (HH*WW)        // 12544
#define GPR (WW/4)        // 28 float4-groups per row
#define GPI (HW/4)        // 3136 float4-groups per image-channel

#define BAND 8            // output rows per block
#define NBAND (HH/BAND)   // 14 bands
#define BLK 256
#define GRID (NN*NBAND)   // 448 blocks

#define TW 114            // padded tile width in u64 words

__global__ __launch_bounds__(BLK)
void fused_kernel(const float* __restrict__ act, const float* __restrict__ wgt,
                  float* __restrict__ out) {
    __shared__ uint64_t tile[BAND + 2][TW];   // 9120 B, zero-padded halo
    __shared__ uint64_t wlds[OO * 9];         // 4608 B packed weights
    __shared__ float bases[9][OO];            // 2304 B boundary-class bases

    const int b = blockIdx.x;
    const int n = b / NBAND;
    const int band = b - n * NBAND;
    const int h0 = band * BAND;
    const int tid = threadIdx.x;
    const bool top = (band == 0);
    const bool bot = (band == NBAND - 1);

    // ---- zero halos (side columns always; top/bottom rows at image edges) ----
    if (tid < BAND + 2) { tile[tid][0] = 0ull; tile[tid][TW - 1] = 0ull; }
    if (top && tid < TW) tile[0][tid] = 0ull;
    if (bot && tid >= BLK - TW) tile[BAND + 1][tid - (BLK - TW)] = 0ull;

    // ---- pack weights into LDS: wlds[o*9+k] bit i = signbit(W[o][i][kh][kw]) ----
    for (int t = tid; t < OO * 9; t += BLK) {
        const int o = t / 9, k = t - o * 9;
        uint32_t lo = 0, hi = 0;
        #pragma unroll
        for (int i = 0; i < 64; ++i) {
            uint32_t s = __float_as_uint(wgt[(o * 64 + i) * 9 + k]) >> 31;
            if (i < 32) lo |= s << i;
            else        hi |= s << (i - 32);
        }
        wlds[t] = ((uint64_t)hi << 32) | lo;
    }

    // ---- pack activation band (+halo rows) into padded LDS tile ----
    const int r_lo = top ? 1 : 0;
    const int r_hi = bot ? BAND : BAND + 1;
    const int ngrp = (r_hi - r_lo + 1) * GPR;        // <= 280
    for (int g = tid; g < ngrp; g += BLK) {
        const int rr = g / GPR;
        const int w4 = g - rr * GPR;
        const int tr = r_lo + rr;
        const int h = h0 - 1 + tr;                    // absolute image row
        const float4* bp = (const float4*)act + (size_t)n * CC * GPI
                         + (size_t)h * GPR + w4;
        uint32_t lo[4] = {0, 0, 0, 0}, hi[4] = {0, 0, 0, 0};
        #pragma unroll
        for (int c = 0; c < 64; ++c) {
            float4 v = bp[(size_t)c * GPI];           // coalesced across lanes
            uint32_t s0 = __float_as_uint(v.x) >> 31;
            uint32_t s1 = __float_as_uint(v.y) >> 31;
            uint32_t s2 = __float_as_uint(v.z) >> 31;
            uint32_t s3 = __float_as_uint(v.w) >> 31;
            if (c < 32) {
                lo[0] |= s0 << c; lo[1] |= s1 << c; lo[2] |= s2 << c; lo[3] |= s3 << c;
            } else {
                const int cc = c - 32;
                hi[0] |= s0 << cc; hi[1] |= s1 << cc; hi[2] |= s2 << cc; hi[3] |= s3 << cc;
            }
        }
        uint64_t* d = &tile[tr][1 + w4 * 4];
        d[0] = ((uint64_t)hi[0] << 32) | lo[0];
        d[1] = ((uint64_t)hi[1] << 32) | lo[1];
        d[2] = ((uint64_t)hi[2] << 32) | lo[2];
        d[3] = ((uint64_t)hi[3] << 32) | lo[3];
    }

    __syncthreads();

    // ---- bases[class][o] = 576 - Sum_{k invalid in class} (64 - 2*popc(w_ok)) ----
    if (tid < OO) {
        const int o = tid;
        int contrib[9];
        #pragma unroll
        for (int k = 0; k < 9; ++k)
            contrib[k] = 64 - 2 * (int)__popcll(wlds[o * 9 + k]);
        #pragma unroll
        for (int ht = 0; ht < 3; ++ht) {
            #pragma unroll
            for (int wt = 0; wt < 3; ++wt) {
                int sum = 0;
                #pragma unroll
                for (int k = 0; k < 9; ++k) {
                    const int kh = k / 3, kw = k - kh * 3;
                    const bool inv = (ht == 0 && kh == 0) || (ht == 2 && kh == 2) ||
                                     (wt == 0 && kw == 0) || (wt == 2 && kw == 2);
                    if (inv) sum += contrib[k];
                }
                bases[ht * 3 + wt][o] = (float)(576 - sum);
            }
        }
    }

    __syncthreads();

    // ---- conv: 4 consecutive output pixels per thread, all 64 o ----
    if (tid >= BAND * GPR) return;                   // 224 active threads
    const int tr = tid / GPR;
    const int w4 = tid - tr * GPR;
    const int w0 = w4 * 4;
    const int h = h0 + tr;

    uint64_t A[3][6];                                // rows h-1..h+1, padded cols w0..w0+5
    #pragma unroll
    for (int r = 0; r < 3; ++r) {
        const ulonglong2* p = (const ulonglong2*)&tile[tr + r][w0];  // 16B aligned
        ulonglong2 u0 = p[0], u1 = p[1], u2 = p[2];
        A[r][0] = u0.x; A[r][1] = u0.y;
        A[r][2] = u1.x; A[r][3] = u1.y;
        A[r][4] = u2.x; A[r][5] = u2.y;
    }

    const int ht = (h == 0) ? 0 : ((h == HH - 1) ? 2 : 1);
    const float* bp0  = bases[ht * 3 + ((w0 == 0) ? 0 : 1)];
    const float* bp12 = bases[ht * 3 + 1];
    const float* bp3  = bases[ht * 3 + ((w0 + 3 == WW - 1) ? 2 : 1)];

    float* op = out + (size_t)n * (OO * HW) + (size_t)h * WW + w0;
    #pragma unroll 2
    for (int o = 0; o < OO; ++o) {
        const uint64_t* wk = &wlds[o * 9];           // wave-uniform -> broadcast reads
        int s0 = 0, s1 = 0, s2 = 0, s3 = 0;
        #pragma unroll
        for (int kh = 0; kh < 3; ++kh) {
            #pragma unroll
            for (int kw = 0; kw < 3; ++kw) {
                const uint64_t wv = wk[kh * 3 + kw];
                s0 += __popcll(A[kh][kw    ] ^ wv);
                s1 += __popcll(A[kh][kw + 1] ^ wv);
                s2 += __popcll(A[kh][kw + 2] ^ wv);
                s3 += __popcll(A[kh][kw + 3] ^ wv);
            }
        }
        float4 v;
        v.x = bp0[o]  - 2.0f * (float)s0;
        v.y = bp12[o] - 2.0f * (float)s1;
        v.z = bp12[o] - 2.0f * (float)s2;
        v.w = bp3[o]  - 2.0f * (float)s3;
        *(float4*)(op + (size_t)o * HW) = v;         // coalesced 16B store
    }
}

extern "C" void kernel_launch(void* const* d_in, const int* in_sizes, int n_in,
                              void* d_out, int out_size, void* d_ws, size_t ws_size,
                              hipStream_t stream) {
    const float* act = (const float*)d_in[0];
    const float* wgt = (const float*)d_in[1];
    float* out = (float*)d_out;
    fused_kernel<<<GRID, BLK, 0, stream>>>(act, wgt, out);
}

// Round 3
// 205.921 us; speedup vs baseline: 1.2038x; 1.2038x over previous
//
#include <hip/hip_runtime.h>
#include <stdint.h>

// Binary conv via bit-pack + XNOR popcount, zero-padded halo + class-correction.
// A: [32,64,112,112] f32, W: [64,64,3,3] f32 (flat), out: [32,64,112,112] f32.
// sign(x) bit = signbit(x); dot over 64 ch = 64 - 2*popc(a ^ w).
// Packed activations live in a zero-padded buffer (halo bits = 0 = all +1 signs);
// the spurious pad contribution is folded into bases[class][o]: out = bases - 2*s.
//
// R3 changes vs R1: 2x grid for pack (2px/thread, raw-bit nt loads), 4x grid for
// conv (o-loop split across 4 blocks), aligned 16B tap loads, nt float4 stores,
// halo-zeroing distributed across pack blocks.

#define NN 32
#define CC 64
#define HH 112
#define WW 112
#define OO 64
#define HW (HH*WW)        // 12544
#define G2 (HW/2)         // 6272 float2-groups per channel plane
#define G4 (HW/4)         // 3136 float4-groups per channel plane

#define PW 116            // padded width in u64 words (2 left, 2 right)
#define PH 114            // padded height (1 top, 1 bottom)
#define PHW (PW*PH)       // 13224 words per image
#define HALO_PER_IMG 680  // 2*116 + 4*112
#define HALO_TOTAL (NN*HALO_PER_IMG)   // 21760

#define BLK 256
#define PACK_BLOCKS (NN*G2/BLK)        // 784
#define CONV_G4BLOCKS (NN*G4/BLK)      // 392
#define OSPLIT 4
#define OS (OO/OSPLIT)                 // 16 output channels per conv block
#define CONV_BLOCKS (CONV_G4BLOCKS*OSPLIT)  // 1568

typedef float f4v __attribute__((ext_vector_type(4)));

// workspace (u64 words): [0,576) wp | [1024,1312) bases(f32[9][64]) | [1536,..) ap

__global__ __launch_bounds__(BLK)
void pack_kernel(const float* __restrict__ act, const float* __restrict__ wgt,
                 uint64_t* __restrict__ ap, uint64_t* __restrict__ wp,
                 float* __restrict__ bases) {
    const int b = blockIdx.x;
    const int tid = threadIdx.x;

    if (b == PACK_BLOCKS) {
        // ---- pack weights: wp[o*9+k] bit i = signbit(W[o][i][kh][kw]) ----
        for (int t = tid; t < OO * 9; t += BLK) {
            const int o = t / 9, k = t - o * 9;
            uint32_t lo = 0, hi = 0;
            #pragma unroll
            for (int i = 0; i < 64; ++i) {
                uint32_t s = __float_as_uint(wgt[(o * 64 + i) * 9 + k]) >> 31;
                if (i < 32) lo |= s << i;
                else        hi |= s << (i - 32);
            }
            wp[t] = ((uint64_t)hi << 32) | lo;
        }
        __syncthreads();
        // ---- bases[class][o] = 576 - Sum_{k invalid in class}(64 - 2*popc(w_ok)) ----
        if (tid < OO) {
            const int o = tid;
            int contrib[9];
            #pragma unroll
            for (int k = 0; k < 9; ++k)
                contrib[k] = 64 - 2 * (int)__popcll(wp[o * 9 + k]);
            #pragma unroll
            for (int ht = 0; ht < 3; ++ht) {
                #pragma unroll
                for (int wt = 0; wt < 3; ++wt) {
                    int sum = 0;
                    #pragma unroll
                    for (int k = 0; k < 9; ++k) {
                        const int kh = k / 3, kw = k - kh * 3;
                        const bool inv = (ht == 0 && kh == 0) || (ht == 2 && kh == 2) ||
                                         (wt == 0 && kw == 0) || (wt == 2 && kw == 2);
                        if (inv) sum += contrib[k];
                    }
                    bases[(ht * 3 + wt) * OO + o] = (float)(576 - sum);
                }
            }
        }
        return;
    }

    // ---- distributed halo zeroing: 28 words per block ----
    if (tid < 28) {
        const int i = b * 28 + tid;
        if (i < HALO_TOTAL) {
            const int n = i / HALO_PER_IMG;
            const int j2 = i - n * HALO_PER_IMG;
            int row, col;
            if (j2 < PW)            { row = 0;      col = j2; }
            else if (j2 < 2 * PW)   { row = PH - 1; col = j2 - PW; }
            else {
                const int j3 = j2 - 2 * PW;
                row = 1 + (j3 >> 2);
                const int s = j3 & 3;
                col = (s < 2) ? s : 112 + s;     // cols 0,1,114,115
            }
            ap[(size_t)n * PHW + (size_t)row * PW + col] = 0ull;
        }
    }

    // ---- pack activations: 2 pixels per thread, raw-bit sign extraction ----
    const int t = b * BLK + tid;                 // float2-group id over N*HW/2
    const int n = t / G2;
    const int g2 = t - n * G2;
    const int h = g2 / (WW / 2);
    const int w2 = g2 - h * (WW / 2);
    const uint64_t* bp = (const uint64_t*)act + (size_t)n * CC * G2 + g2;
    uint32_t lo0 = 0, lo1 = 0, hi0 = 0, hi1 = 0;
    #pragma unroll
    for (int c = 0; c < 64; ++c) {
        const uint64_t r = __builtin_nontemporal_load(bp + (size_t)c * G2);
        const uint32_t s0 = (uint32_t)(r >> 31) & 1u;   // sign of low float (even col)
        const uint32_t s1 = (uint32_t)(r >> 63);        // sign of high float (odd col)
        if (c < 32) { lo0 |= s0 << c;        lo1 |= s1 << c; }
        else        { hi0 |= s0 << (c - 32); hi1 |= s1 << (c - 32); }
    }
    ulonglong2 v;
    v.x = ((uint64_t)hi0 << 32) | lo0;
    v.y = ((uint64_t)hi1 << 32) | lo1;
    // image pixel (h, w2*2+px) -> padded (h+1, w2*2+2+px); 16B aligned
    *(ulonglong2*)(ap + (size_t)n * PHW + (size_t)(h + 1) * PW + (w2 * 2 + 2)) = v;
}

__global__ __launch_bounds__(BLK)
void conv_kernel(const uint64_t* __restrict__ ap, const uint64_t* __restrict__ wp,
                 const float* __restrict__ bases, float* __restrict__ out) {
    const int bid = blockIdx.x;
    const int og = bid & (OSPLIT - 1);           // o-group: uniform per block
    const int gb = bid >> 2;
    const int t = gb * BLK + threadIdx.x;        // 4-pixel group id over N*HW/4
    const int n = t / G4;
    const int g = t - n * G4;
    const int h = g / (WW / 4);
    const int w4 = g - h * (WW / 4);
    const int w0 = w4 * 4;

    // taps: padded rows h..h+2, padded cols w0+1..w0+6; load 8 words aligned
    uint64_t A[3][8];
    const uint64_t* rb = ap + (size_t)n * PHW + (size_t)h * PW + w0;  // even word
    #pragma unroll
    for (int r = 0; r < 3; ++r) {
        const ulonglong2* p = (const ulonglong2*)(rb + (size_t)r * PW);
        const ulonglong2 u0 = p[0], u1 = p[1], u2 = p[2], u3 = p[3];
        A[r][0] = u0.x; A[r][1] = u0.y; A[r][2] = u1.x; A[r][3] = u1.y;
        A[r][4] = u2.x; A[r][5] = u2.y; A[r][6] = u3.x; A[r][7] = u3.y;
    }

    const int ht = (h == 0) ? 0 : ((h == HH - 1) ? 2 : 1);
    const float* bp0  = bases + (ht * 3 + ((w0 == 0) ? 0 : 1)) * OO;
    const float* bp12 = bases + (ht * 3 + 1) * OO;
    const float* bp3  = bases + (ht * 3 + ((w0 + 3 == WW - 1) ? 2 : 1)) * OO;

    float* op = out + (size_t)n * (OO * HW) + (size_t)h * WW + w0;
    const int o0 = og * OS;
    #pragma unroll 2
    for (int o = o0; o < o0 + OS; ++o) {
        const uint64_t* wk = wp + o * 9;         // wave-uniform -> scalar loads
        int s0 = 0, s1 = 0, s2 = 0, s3 = 0;
        #pragma unroll
        for (int kh = 0; kh < 3; ++kh) {
            #pragma unroll
            for (int kw = 0; kw < 3; ++kw) {
                const uint64_t wv = wk[kh * 3 + kw];
                // pixel j tap kw -> padded col w0+1+j+kw -> A[kh][1+j+kw]
                s0 += __popcll(A[kh][1 + kw] ^ wv);
                s1 += __popcll(A[kh][2 + kw] ^ wv);
                s2 += __popcll(A[kh][3 + kw] ^ wv);
                s3 += __popcll(A[kh][4 + kw] ^ wv);
            }
        }
        f4v v;
        v.x = bp0[o]  - 2.0f * (float)s0;
        v.y = bp12[o] - 2.0f * (float)s1;
        v.z = bp12[o] - 2.0f * (float)s2;
        v.w = bp3[o]  - 2.0f * (float)s3;
        __builtin_nontemporal_store(v, (f4v*)(op + (size_t)o * HW));  // 16B, never re-read
    }
}

extern "C" void kernel_launch(void* const* d_in, const int* in_sizes, int n_in,
                              void* d_out, int out_size, void* d_ws, size_t ws_size,
                              hipStream_t stream) {
    const float* act = (const float*)d_in[0];
    const float* wgt = (const float*)d_in[1];
    float* out = (float*)d_out;

    uint64_t* wp = (uint64_t*)d_ws;              // 576 words (reserve 1024)
    float* bases = (float*)(wp + 1024);          // f32[9][64] (reserve 512 words)
    uint64_t* ap = wp + 1536;                    // 32*13224 words ~= 3.39 MB

    pack_kernel<<<PACK_BLOCKS + 1, BLK, 0, stream>>>(act, wgt, ap, wp, bases);
    conv_kernel<<<CONV_BLOCKS, BLK, 0, stream>>>(ap, wp, bases, out);
}

// Round 4
// 204.925 us; speedup vs baseline: 1.2096x; 1.0049x over previous
//
#include <hip/hip_runtime.h>
#include <stdint.h>

// Binary conv via bit-pack + XNOR popcount, zero-padded halo + class-correction.
// A: [32,64,112,112] f32, W: [64,64,3,3] f32 (flat), out: [32,64,112,112] f32.
// sign(x) bit = signbit(x); dot over 64 ch = 64 - 2*popc(a ^ w).
// Packed activations live in a zero-padded buffer (halo bits = 0 = all +1 signs);
// the spurious pad contribution is folded into bases[class][o]: out = bases - 2*s.
//
// R4 change: pack restructured for memory-level parallelism. Channel-split x4:
// each thread loads 16 channels x uint4 (16 independent 16B loads), 1568 blocks
// (~24 waves/CU vs 6), partials combined via a conflict-free 4KB LDS transpose;
// wave 0 assembles and stores aligned 16B words. Conv unchanged from R3.

#define NN 32
#define CC 64
#define HH 112
#define WW 112
#define OO 64
#define HW (HH*WW)        // 12544
#define G4 (HW/4)         // 3136 float4-groups per channel plane

#define PW 116            // padded width in u64 words (2 left, 2 right)
#define PH 114            // padded height (1 top, 1 bottom)
#define PHW (PW*PH)       // 13224 words per image
#define HALO_PER_IMG 680  // 2*116 + 4*112
#define HALO_TOTAL (NN*HALO_PER_IMG)   // 21760

#define BLK 256
#define PACK_BLOCKS (NN*G4/64)         // 1568: 64 px-groups (4px) per block
#define CONV_G4BLOCKS (NN*G4/BLK)      // 392
#define OSPLIT 4
#define OS (OO/OSPLIT)                 // 16 output channels per conv block
#define CONV_BLOCKS (CONV_G4BLOCKS*OSPLIT)  // 1568

typedef float f4v __attribute__((ext_vector_type(4)));

// workspace (u64 words): [0,576) wp | [1024,1312) bases(f32[9][64]) | [1536,..) ap

__global__ __launch_bounds__(BLK)
void pack_kernel(const float* __restrict__ act, const float* __restrict__ wgt,
                 uint64_t* __restrict__ ap, uint64_t* __restrict__ wp,
                 float* __restrict__ bases) {
    const int b = blockIdx.x;
    const int tid = threadIdx.x;

    if (b == PACK_BLOCKS) {
        // ---- pack weights: wp[o*9+k] bit i = signbit(W[o][i][kh][kw]) ----
        for (int t = tid; t < OO * 9; t += BLK) {
            const int o = t / 9, k = t - o * 9;
            uint32_t lo = 0, hi = 0;
            #pragma unroll
            for (int i = 0; i < 64; ++i) {
                uint32_t s = __float_as_uint(wgt[(o * 64 + i) * 9 + k]) >> 31;
                if (i < 32) lo |= s << i;
                else        hi |= s << (i - 32);
            }
            wp[t] = ((uint64_t)hi << 32) | lo;
        }
        __syncthreads();
        // ---- bases[class][o] = 576 - Sum_{k invalid in class}(64 - 2*popc(w_ok)) ----
        if (tid < OO) {
            const int o = tid;
            int contrib[9];
            #pragma unroll
            for (int k = 0; k < 9; ++k)
                contrib[k] = 64 - 2 * (int)__popcll(wp[o * 9 + k]);
            #pragma unroll
            for (int ht = 0; ht < 3; ++ht) {
                #pragma unroll
                for (int wt = 0; wt < 3; ++wt) {
                    int sum = 0;
                    #pragma unroll
                    for (int k = 0; k < 9; ++k) {
                        const int kh = k / 3, kw = k - kh * 3;
                        const bool inv = (ht == 0 && kh == 0) || (ht == 2 && kh == 2) ||
                                         (wt == 0 && kw == 0) || (wt == 2 && kw == 2);
                        if (inv) sum += contrib[k];
                    }
                    bases[(ht * 3 + wt) * OO + o] = (float)(576 - sum);
                }
            }
        }
        return;
    }

    // ---- distributed halo zeroing: 14 words per block ----
    if (tid < 14) {
        const int i = b * 14 + tid;
        if (i < HALO_TOTAL) {
            const int n = i / HALO_PER_IMG;
            const int j2 = i - n * HALO_PER_IMG;
            int row, col;
            if (j2 < PW)            { row = 0;      col = j2; }
            else if (j2 < 2 * PW)   { row = PH - 1; col = j2 - PW; }
            else {
                const int j3 = j2 - 2 * PW;
                row = 1 + (j3 >> 2);
                const int s = j3 & 3;
                col = (s < 2) ? s : 112 + s;     // cols 0,1,114,115
            }
            ap[(size_t)n * PHW + (size_t)row * PW + col] = 0ull;
        }
    }

    // ---- pack activations: channel-split x4, 16 independent uint4 loads ----
    // thread t: q = t>>6 (channel quarter), p = t&63 (px-group within block)
    __shared__ uint32_t sm[4][4][64];            // [px][q][p], conflict-free
    const int q = tid >> 6;
    const int p = tid & 63;
    const int G = b * 64 + p;                    // global 4px-group id
    const int n = G / G4;
    const int g = G - n * G4;
    const int h = g / (WW / 4);
    const int w4 = g - h * (WW / 4);

    const uint4* bp = (const uint4*)act + ((size_t)n * CC + q * 16) * G4 + g;
    uint32_t w0a = 0, w1a = 0, w2a = 0, w3a = 0; // bit j = sign of channel q*16+j
    #pragma unroll
    for (int j = 0; j < 16; ++j) {
        const uint4 v = bp[(size_t)j * G4];      // independent: deep MLP
        w0a |= (v.x >> 31) << j;
        w1a |= (v.y >> 31) << j;
        w2a |= (v.z >> 31) << j;
        w3a |= (v.w >> 31) << j;
    }
    sm[0][q][p] = w0a;
    sm[1][q][p] = w1a;
    sm[2][q][p] = w2a;
    sm[3][q][p] = w3a;
    __syncthreads();

    if (tid < 64) {                              // wave 0 assembles + stores
        uint64_t A[4];
        #pragma unroll
        for (int j = 0; j < 4; ++j) {
            const uint32_t lo = sm[j][0][p] | (sm[j][1][p] << 16);
            const uint32_t hi = sm[j][2][p] | (sm[j][3][p] << 16);
            A[j] = ((uint64_t)hi << 32) | lo;
        }
        // image pixel (h, w4*4+px) -> padded (h+1, w4*4+2+px); 16B aligned
        uint64_t* dst = ap + (size_t)n * PHW + (size_t)(h + 1) * PW + (w4 * 4 + 2);
        ulonglong2 v0, v1;
        v0.x = A[0]; v0.y = A[1];
        v1.x = A[2]; v1.y = A[3];
        ((ulonglong2*)dst)[0] = v0;
        ((ulonglong2*)dst)[1] = v1;
    }
}

__global__ __launch_bounds__(BLK)
void conv_kernel(const uint64_t* __restrict__ ap, const uint64_t* __restrict__ wp,
                 const float* __restrict__ bases, float* __restrict__ out) {
    const int bid = blockIdx.x;
    const int og = bid & (OSPLIT - 1);           // o-group: uniform per block
    const int gb = bid >> 2;
    const int t = gb * BLK + threadIdx.x;        // 4-pixel group id over N*HW/4
    const int n = t / G4;
    const int g = t - n * G4;
    const int h = g / (WW / 4);
    const int w4 = g - h * (WW / 4);
    const int w0 = w4 * 4;

    // taps: padded rows h..h+2, padded cols w0+1..w0+6; load 8 words aligned
    uint64_t A[3][8];
    const uint64_t* rb = ap + (size_t)n * PHW + (size_t)h * PW + w0;  // even word
    #pragma unroll
    for (int r = 0; r < 3; ++r) {
        const ulonglong2* p = (const ulonglong2*)(rb + (size_t)r * PW);
        const ulonglong2 u0 = p[0], u1 = p[1], u2 = p[2], u3 = p[3];
        A[r][0] = u0.x; A[r][1] = u0.y; A[r][2] = u1.x; A[r][3] = u1.y;
        A[r][4] = u2.x; A[r][5] = u2.y; A[r][6] = u3.x; A[r][7] = u3.y;
    }

    const int ht = (h == 0) ? 0 : ((h == HH - 1) ? 2 : 1);
    const float* bp0  = bases + (ht * 3 + ((w0 == 0) ? 0 : 1)) * OO;
    const float* bp12 = bases + (ht * 3 + 1) * OO;
    const float* bp3  = bases + (ht * 3 + ((w0 + 3 == WW - 1) ? 2 : 1)) * OO;

    float* op = out + (size_t)n * (OO * HW) + (size_t)h * WW + w0;
    const int o0 = og * OS;
    #pragma unroll 2
    for (int o = o0; o < o0 + OS; ++o) {
        const uint64_t* wk = wp + o * 9;         // wave-uniform -> scalar loads
        int s0 = 0, s1 = 0, s2 = 0, s3 = 0;
        #pragma unroll
        for (int kh = 0; kh < 3; ++kh) {
            #pragma unroll
            for (int kw = 0; kw < 3; ++kw) {
                const uint64_t wv = wk[kh * 3 + kw];
                // pixel j tap kw -> padded col w0+1+j+kw -> A[kh][1+j+kw]
                s0 += __popcll(A[kh][1 + kw] ^ wv);
                s1 += __popcll(A[kh][2 + kw] ^ wv);
                s2 += __popcll(A[kh][3 + kw] ^ wv);
                s3 += __popcll(A[kh][4 + kw] ^ wv);
            }
        }
        f4v v;
        v.x = bp0[o]  - 2.0f * (float)s0;
        v.y = bp12[o] - 2.0f * (float)s1;
        v.z = bp12[o] - 2.0f * (float)s2;
        v.w = bp3[o]  - 2.0f * (float)s3;
        __builtin_nontemporal_store(v, (f4v*)(op + (size_t)o * HW));  // 16B, never re-read
    }
}

extern "C" void kernel_launch(void* const* d_in, const int* in_sizes, int n_in,
                              void* d_out, int out_size, void* d_ws, size_t ws_size,
                              hipStream_t stream) {
    const float* act = (const float*)d_in[0];
    const float* wgt = (const float*)d_in[1];
    float* out = (float*)d_out;

    uint64_t* wp = (uint64_t*)d_ws;              // 576 words (reserve 1024)
    float* bases = (float*)(wp + 1024);          // f32[9][64] (reserve 512 words)
    uint64_t* ap = wp + 1536;                    // 32*13224 words ~= 3.39 MB

    pack_kernel<<<PACK_BLOCKS + 1, BLK, 0, stream>>>(act, wgt, ap, wp, bases);
    conv_kernel<<<CONV_BLOCKS, BLK, 0, stream>>>(ap, wp, bases, out);
}